// Round 8
// baseline (453.843 us; speedup 1.0000x reference)
//
#include <hip/hip_runtime.h>
#include <climits>

#define IN_F 4096
#define OUT_F 4096
#define BATCH 4096
#define NPART 1024   // partial-reduction slots (fallback path)

typedef __bf16 bf16x8 __attribute__((ext_vector_type(8)));
typedef float f32x4 __attribute__((ext_vector_type(4)));
typedef unsigned short u16x8 __attribute__((ext_vector_type(8)));

__device__ __forceinline__ unsigned short f2bf_rne(float f) {
  unsigned int u = __float_as_uint(f);
  u += 0x7fffu + ((u >> 16) & 1u);
  return (unsigned short)(u >> 16);
}

__device__ __forceinline__ u16x8 cvt8f(float4 a, float4 b) {
  u16x8 h;
  h[0] = f2bf_rne(a.x); h[1] = f2bf_rne(a.y); h[2] = f2bf_rne(a.z); h[3] = f2bf_rne(a.w);
  h[4] = f2bf_rne(b.x); h[5] = f2bf_rne(b.y); h[6] = f2bf_rne(b.z); h[7] = f2bf_rne(b.w);
  return h;
}
__device__ __forceinline__ u16x8 cvt8i(int4 a, int4 b) {
  u16x8 h;
  h[0] = f2bf_rne((float)a.x); h[1] = f2bf_rne((float)a.y);
  h[2] = f2bf_rne((float)a.z); h[3] = f2bf_rne((float)a.w);
  h[4] = f2bf_rne((float)b.x); h[5] = f2bf_rne((float)b.y);
  h[6] = f2bf_rne((float)b.z); h[7] = f2bf_rne((float)b.w);
  return h;
}

// ---------------- async global->LDS, 16B per lane, wave-uniform LDS base ----------------
__device__ __forceinline__ void load_lds16(const unsigned short* g, unsigned short* l) {
  __builtin_amdgcn_global_load_lds(
      (const __attribute__((address_space(1))) unsigned int*)g,
      (__attribute__((address_space(3))) unsigned int*)l, 16, 0, 0);
}

#define VMW(n) asm volatile("s_waitcnt vmcnt(" #n ")" ::: "memory")
#define CFENCE asm volatile("" ::: "memory")

// R6 GEMM K-iteration (best measured: 137.6us gemm, MfmaUtil 43%, conflicts 0)
#define GITER(C, CA, CB, NA, NB, PF, LDN, CHK)                                      \
  {                                                                                 \
    bf16x8 a2_[4];                                                                  \
    _Pragma("unroll") for (int i = 0; i < 4; ++i)                                   \
        a2_[i] = *(const bf16x8*)&As[(C)][(wm + 64 + i * 16 + r16) * 32 + pc];      \
    if (PF) {                                                                       \
      load_lds16(srcA0 + kb + ((C) + 3) * 32, &As[((C) + 3) & 3][dst0]);            \
      load_lds16(srcA1 + kb + ((C) + 3) * 32, &As[((C) + 3) & 3][dst1]);            \
    }                                                                               \
    __builtin_amdgcn_s_setprio(1);                                                  \
    _Pragma("unroll") for (int mi = 0; mi < 4; ++mi)                                \
        _Pragma("unroll") for (int ni = 0; ni < 4; ++ni)                            \
            acc[mi][ni] = __builtin_amdgcn_mfma_f32_16x16x32_bf16(                  \
                CA[mi], CB[ni], acc[mi][ni], 0, 0, 0);                              \
    __builtin_amdgcn_s_setprio(0);                                                  \
    if (LDN) {                                                                      \
      _Pragma("unroll") for (int i = 0; i < 4; ++i) {                               \
        NA[i] = *(const bf16x8*)&As[((C) + 1) & 3][(wm + i * 16 + r16) * 32 + pc];  \
        NB[i] = *(const bf16x8*)&Bs[((C) + 1) & 3][(wn + i * 16 + r16) * 32 + pc];  \
      }                                                                             \
    }                                                                               \
    if (PF) {                                                                       \
      load_lds16(srcB0 + kb + ((C) + 3) * 32, &Bs[((C) + 3) & 3][dst0]);            \
      load_lds16(srcB1 + kb + ((C) + 3) * 32, &Bs[((C) + 3) & 3][dst1]);            \
    }                                                                               \
    __builtin_amdgcn_s_setprio(1);                                                  \
    _Pragma("unroll") for (int mi = 0; mi < 4; ++mi)                                \
        _Pragma("unroll") for (int ni = 0; ni < 4; ++ni)                            \
            acc[4 + mi][ni] = __builtin_amdgcn_mfma_f32_16x16x32_bf16(              \
                a2_[mi], CB[ni], acc[4 + mi][ni], 0, 0, 0);                         \
    __builtin_amdgcn_s_setprio(0);                                                  \
    CHK;                                                                            \
    __builtin_amdgcn_s_barrier();                                                   \
    CFENCE;                                                                         \
  }

// ---------------- R11: SINGLE-LAUNCH fused convert + grid-barrier + R6 GEMM ----------------
// Evidence: non-GEMM residual was 168-176us across six 3-launch variants (invariant to
// conv internals) and dropped to ~105us at 2 launches (R10) -> ~50us/launch overhead.
// So: ONE launch. Phase 1: block b converts x/wq rows [16b,16b+16) to bf16 workspace
// (proven 16B-store loop), folds rowsums, 1 atomicMin/Max per block for weight range.
// Grid barrier: 256 blocks x 128KB LDS = hard 1 block/CU -> all co-resident (R6 already
// ran 1 block/CU); counter reset each launch via hipMemsetAsync (graph-replay safe);
// bounded spin (~0.2s) turns any residency surprise into a flagged wrong answer, not a hang.
// Phase 2: R6 GEMM verbatim. Affine scalars computed per-thread in the epilogue from the
// two atomic words (consumed ONLY there — no pre-reduction kernel needed).
__global__ __launch_bounds__(512, 2) void k_fused(
    const float* __restrict__ X,      // x  fp32 [BATCH][IN_F]
    const int* __restrict__ WQ,       // q  int32 [OUT_F][IN_F]
    const int* __restrict__ bq,
    const float* __restrict__ wmn, const float* __restrict__ wmx,
    const float* __restrict__ bmn, const float* __restrict__ bmx,
    unsigned short* __restrict__ xb,
    unsigned short* __restrict__ qb,
    float* __restrict__ rowsum,
    int* __restrict__ qminw, int* __restrict__ qmaxw,
    unsigned int* __restrict__ ctr,
    float* __restrict__ C) {
  __shared__ __align__(16) unsigned short As[4][8192];   // 128 KB -> 1 block/CU
  __shared__ __align__(16) unsigned short Bs[4][8192];

  const int tid = threadIdx.x;
  const int w = tid >> 6;
  const int lane = tid & 63;
  const int bid = blockIdx.x;       // 0..255

  // ================= phase 1: convert 16 rows of x and wq =================
  {
    int vmin = INT_MAX, vmax = INT_MIN;
#pragma unroll
    for (int rr = 0; rr < 2; ++rr) {
      const int row = bid * 16 + w * 2 + rr;
      // ---- x row -> bf16 + rowsum ----
      const float4* xr = (const float4*)(X + (size_t)row * IN_F);
      u16x8* xbr = (u16x8*)(xb + (size_t)row * IN_F);
      float s = 0.f;
#pragma unroll
      for (int it = 0; it < IN_F / 8 / 64; ++it) {   // 8 iters
        const int i = it * 64 + lane;
        float4 v0 = xr[2 * i];
        float4 v1 = xr[2 * i + 1];
        s += ((v0.x + v0.y) + (v0.z + v0.w)) + ((v1.x + v1.y) + (v1.z + v1.w));
        xbr[i] = cvt8f(v0, v1);
      }
      for (int off = 32; off > 0; off >>= 1) s += __shfl_down(s, off);
      if (lane == 0) rowsum[row] = s;
      // ---- wq row -> bf16 + min/max ----
      const int4* qr = (const int4*)(WQ + (size_t)row * IN_F);
      u16x8* qbr = (u16x8*)(qb + (size_t)row * IN_F);
#pragma unroll
      for (int it = 0; it < IN_F / 8 / 64; ++it) {
        const int i = it * 64 + lane;
        int4 a = qr[2 * i];
        int4 b = qr[2 * i + 1];
        vmin = min(vmin, min(min(min(a.x, a.y), min(a.z, a.w)),
                             min(min(b.x, b.y), min(b.z, b.w))));
        vmax = max(vmax, max(max(max(a.x, a.y), max(a.z, a.w)),
                             max(max(b.x, b.y), max(b.z, b.w))));
        qbr[i] = cvt8i(a, b);
      }
    }
    for (int off = 32; off > 0; off >>= 1) {
      vmin = min(vmin, __shfl_down(vmin, off));
      vmax = max(vmax, __shfl_down(vmax, off));
    }
    if (lane == 0) {
      atomicMin(qminw, vmin);
      atomicMax(qmaxw, vmax);
    }
  }

  // ================= grid barrier (all 256 blocks co-resident) =================
  __threadfence();          // publish this thread's stores device-wide
  __syncthreads();          // whole block done + fenced
  if (tid == 0) {
    __hip_atomic_fetch_add(ctr, 1u, __ATOMIC_RELEASE, __HIP_MEMORY_SCOPE_AGENT);
    int guard = 0;
    while (__hip_atomic_load(ctr, __ATOMIC_ACQUIRE, __HIP_MEMORY_SCOPE_AGENT) < 256u &&
           guard < 2000000) {
      __builtin_amdgcn_s_sleep(2);
      ++guard;
    }
  }
  __syncthreads();
  // per-thread acquire: orders all phase-2 loads after the barrier, invalidates stale cache
  (void)__hip_atomic_load(ctr, __ATOMIC_ACQUIRE, __HIP_MEMORY_SCOPE_AGENT);

  // ================= phase 2: R6 GEMM on bf16 workspace =================
  const int bm = (bid & 15) * 256;
  const int bn = (bid >> 4) * 256;

  const int wm = (w & 1) * 128;    // wave's 128x64 output subtile
  const int wn = (w >> 1) * 64;
  const int r16 = lane & 15;
  const int q = lane >> 4;
  const int pc = (q ^ ((r16 >> 1) & 3)) * 8;   // swizzled fragment-read chunk

  const int cA0 = w * 128 + lane;
  const int rowS0 = cA0 >> 2;
  const int colS0 = ((cA0 & 3) ^ ((rowS0 >> 1) & 3)) * 8;   // pre-swizzled global source
  const int cA1 = cA0 + 64;
  const int rowS1 = cA1 >> 2;
  const int colS1 = ((cA1 & 3) ^ ((rowS1 >> 1) & 3)) * 8;
  const unsigned short* srcA0 = xb + (size_t)(bm + rowS0) * IN_F + colS0;
  const unsigned short* srcA1 = xb + (size_t)(bm + rowS1) * IN_F + colS1;
  const unsigned short* srcB0 = qb + (size_t)(bn + rowS0) * IN_F + colS0;
  const unsigned short* srcB1 = qb + (size_t)(bn + rowS1) * IN_F + colS1;
  const int dst0 = w * 1024;
  const int dst1 = w * 1024 + 512;

  f32x4 acc[8][4] = {};
  bf16x8 fa0[4], fb0[4], fa1[4], fb1[4];

  // prologue: stage tiles 0,1,2 into slots 0,1,2
#pragma unroll
  for (int t = 0; t < 3; ++t) {
    load_lds16(srcA0 + t * 32, &As[t][dst0]);
    load_lds16(srcA1 + t * 32, &As[t][dst1]);
    load_lds16(srcB0 + t * 32, &Bs[t][dst0]);
    load_lds16(srcB1 + t * 32, &Bs[t][dst1]);
  }
  VMW(4);   // tiles 0,1 retired (tile 2 in flight)
  __builtin_amdgcn_s_barrier();
  CFENCE;
#pragma unroll
  for (int i = 0; i < 4; ++i) {
    fa0[i] = *(const bf16x8*)&As[0][(wm + i * 16 + r16) * 32 + pc];
    fb0[i] = *(const bf16x8*)&Bs[0][(wn + i * 16 + r16) * 32 + pc];
  }

  for (int u = 0; u < 31; ++u) {
    const int kb = u * 128;
    GITER(0, fa0, fb0, fa1, fb1, 1, 1, VMW(4));
    GITER(1, fa1, fb1, fa0, fb0, 1, 1, VMW(4));
    GITER(2, fa0, fb0, fa1, fb1, 1, 1, VMW(4));
    GITER(3, fa1, fb1, fa0, fb0, 1, 1, VMW(4));
  }
  {
    const int kb = 31 * 128;
    GITER(0, fa0, fb0, fa1, fb1, 1, 1, VMW(4));   // stages tile 127 (last)
    GITER(1, fa1, fb1, fa0, fb0, 0, 1, VMW(0));   // drain
    GITER(2, fa0, fb0, fa1, fb1, 0, 1, ((void)0));
    GITER(3, fa1, fb1, fa0, fb0, 0, 0, ((void)0));
  }

  // ---- epilogue: affine scalars computed per-thread from atomic words ----
  const int qmin = *qminw;
  const int qmax = *qmaxw;
  const float wsc = (*wmx - *wmn) / (float)(qmax - qmin);
  const float wbe = *wmn - wsc * (float)qmin;
  // bias min/max: |bq|<=127, OUT_F=4096 values — reduce redundantly? No: bias range is
  // over bq only; do a per-thread strided scan (4096/512=8 loads, L2-hot, one-time).
  int bmin_ = INT_MAX, bmax_ = INT_MIN;
  for (int i = tid; i < OUT_F; i += 512) {
    int v = bq[i];
    bmin_ = min(bmin_, v);
    bmax_ = max(bmax_, v);
  }
  for (int off = 32; off > 0; off >>= 1) {
    bmin_ = min(bmin_, __shfl_down(bmin_, off));
    bmax_ = max(bmax_, __shfl_down(bmax_, off));
  }
  __shared__ int rbr[8][2];
  if (lane == 0) { rbr[w][0] = bmin_; rbr[w][1] = bmax_; }
  __syncthreads();
  int qbmin = rbr[0][0], qbmax = rbr[0][1];
#pragma unroll
  for (int i = 1; i < 8; ++i) {
    qbmin = min(qbmin, rbr[i][0]);
    qbmax = max(qbmax, rbr[i][1]);
  }
  const float bsc = (*bmx - *bmn) / (float)(qbmax - qbmin);
  const float bbe = *bmn - bsc * (float)qbmin;

#pragma unroll
  for (int ni = 0; ni < 4; ++ni) {
    const int gn = bn + wn + ni * 16 + r16;            // C/D: col = lane&15
    const float bdq = bsc * (float)bq[gn] + bbe;
#pragma unroll
    for (int mi = 0; mi < 8; ++mi) {
      const int gm0 = bm + wm + mi * 16 + q * 4;       // C/D: row = quad*4 + reg
#pragma unroll
      for (int r = 0; r < 4; ++r) {
        const int gm = gm0 + r;
        C[(size_t)gm * OUT_F + gn] = wsc * acc[mi][ni][r] + wbe * rowsum[gm] + bdq;
      }
    }
  }
}

// ---------------- fallback path (workspace too small) ----------------
__global__ __launch_bounds__(256) void k_wmm(const int* __restrict__ q,
                                             int* __restrict__ pmin,
                                             int* __restrict__ pmax) {
  const int n4 = (OUT_F * IN_F) / 4;
  const int stride = gridDim.x * blockDim.x;
  int vmin = INT_MAX, vmax = INT_MIN;
  const int4* q4 = (const int4*)q;
  for (int i = blockIdx.x * blockDim.x + threadIdx.x; i < n4; i += stride) {
    int4 v = q4[i];
    vmin = min(vmin, min(min(v.x, v.y), min(v.z, v.w)));
    vmax = max(vmax, max(max(v.x, v.y), max(v.z, v.w)));
  }
  for (int off = 32; off > 0; off >>= 1) {
    vmin = min(vmin, __shfl_down(vmin, off));
    vmax = max(vmax, __shfl_down(vmax, off));
  }
  __shared__ int rmin[4], rmax[4];
  const int wave = threadIdx.x >> 6;
  if ((threadIdx.x & 63) == 0) { rmin[wave] = vmin; rmax[wave] = vmax; }
  __syncthreads();
  if (threadIdx.x == 0) {
    pmin[blockIdx.x] = min(min(rmin[0], rmin[1]), min(rmin[2], rmin[3]));
    pmax[blockIdx.x] = max(max(rmax[0], rmax[1]), max(rmax[2], rmax[3]));
  }
}

__global__ __launch_bounds__(256) void k_scal(const int* __restrict__ pmin,
                                              const int* __restrict__ pmax, int npart,
                                              const int* __restrict__ bq,
                                              const float* __restrict__ wmn,
                                              const float* __restrict__ wmx,
                                              const float* __restrict__ bmn,
                                              const float* __restrict__ bmx,
                                              float* __restrict__ scal) {
  int vmin = INT_MAX, vmax = INT_MIN;
  for (int i = threadIdx.x; i < npart; i += 256) {
    vmin = min(vmin, pmin[i]);
    vmax = max(vmax, pmax[i]);
  }
  int bmin = INT_MAX, bmaxv = INT_MIN;
  for (int i = threadIdx.x; i < OUT_F; i += 256) {
    int v = bq[i];
    bmin = min(bmin, v);
    bmaxv = max(bmaxv, v);
  }
  for (int off = 32; off > 0; off >>= 1) {
    vmin = min(vmin, __shfl_down(vmin, off));
    vmax = max(vmax, __shfl_down(vmax, off));
    bmin = min(bmin, __shfl_down(bmin, off));
    bmaxv = max(bmaxv, __shfl_down(bmaxv, off));
  }
  __shared__ int r[4][4];
  const int wave = threadIdx.x >> 6;
  if ((threadIdx.x & 63) == 0) {
    r[wave][0] = vmin; r[wave][1] = vmax; r[wave][2] = bmin; r[wave][3] = bmaxv;
  }
  __syncthreads();
  if (threadIdx.x == 0) {
    int qmin = min(min(r[0][0], r[1][0]), min(r[2][0], r[3][0]));
    int qmax = max(max(r[0][1], r[1][1]), max(r[2][1], r[3][1]));
    int qbmin = min(min(r[0][2], r[1][2]), min(r[2][2], r[3][2]));
    int qbmax = max(max(r[0][3], r[1][3]), max(r[2][3], r[3][3]));
    float ws = (*wmx - *wmn) / (float)(qmax - qmin);
    scal[0] = ws;
    scal[1] = *wmn - ws * (float)qmin;
    float bs = (*bmx - *bmn) / (float)(qbmax - qbmin);
    scal[2] = bs;
    scal[3] = *bmn - bs * (float)qbmin;
  }
}

__global__ void k_naive(const float* __restrict__ x, const int* __restrict__ wq,
                        const int* __restrict__ bq, const float* __restrict__ scal,
                        float* __restrict__ out) {
  const int o = blockIdx.x * blockDim.x + threadIdx.x;
  const int b = blockIdx.y;
  const float* xr = x + (size_t)b * IN_F;
  const int* wr = wq + (size_t)o * IN_F;
  float s = 0.f, sx = 0.f;
  for (int k = 0; k < IN_F; ++k) {
    float xv = xr[k];
    s += xv * (float)wr[k];
    sx += xv;
  }
  out[(size_t)b * OUT_F + o] =
      scal[0] * s + scal[1] * sx + scal[2] * (float)bq[o] + scal[3];
}

extern "C" void kernel_launch(void* const* d_in, const int* in_sizes, int n_in,
                              void* d_out, int out_size, void* d_ws, size_t ws_size,
                              hipStream_t stream) {
  const float* x = (const float*)d_in[0];
  const int* wq = (const int*)d_in[1];
  const int* bq = (const int*)d_in[2];
  const float* wmn = (const float*)d_in[3];
  const float* wmx = (const float*)d_in[4];
  const float* bmn = (const float*)d_in[5];
  const float* bmx = (const float*)d_in[6];
  float* out = (float*)d_out;

  char* ws = (char*)d_ws;
  unsigned int* ctr = (unsigned int*)ws;                     // 4 B   (reset each launch)
  int* qminw = (int*)(ws + 16);                              // 4 B   (memset 0x7f)
  int* qmaxw = (int*)(ws + 20);                              // 4 B   (memset 0x80)
  float* scal = (float*)(ws + 32);                           // 16 B  (fallback)
  float* rowsum = (float*)(ws + 64);                         // 16 KB
  int* pmin = (int*)(ws + 16448);                            // 4 KB  (fallback)
  int* pmax = (int*)(ws + 16448 + NPART * 4);                // 4 KB  (fallback)
  unsigned short* xb = (unsigned short*)(ws + 32768);
  unsigned short* qb = xb + (size_t)BATCH * IN_F;
  const size_t needed = 32768 + (size_t)BATCH * IN_F * 2 + (size_t)OUT_F * IN_F * 2;

  if (ws_size >= needed) {
    hipMemsetAsync(ctr, 0, 4, stream);
    hipMemsetAsync(qminw, 0x7f, 4, stream);   // 0x7f7f7f7f = huge positive
    hipMemsetAsync(qmaxw, 0x80, 4, stream);   // 0x80808080 = huge negative
    k_fused<<<256, 512, 0, stream>>>(x, wq, bq, wmn, wmx, bmn, bmx,
                                     xb, qb, rowsum, qminw, qmaxw, ctr, out);
  } else {
    k_wmm<<<NPART, 256, 0, stream>>>(wq, pmin, pmax);
    k_scal<<<1, 256, 0, stream>>>(pmin, pmax, NPART, bq, wmn, wmx, bmn, bmx, scal);
    k_naive<<<dim3(OUT_F / 256, BATCH), 256, 0, stream>>>(x, wq, bq, scal, out);
  }
}